// Round 10
// baseline (184.644 us; speedup 1.0000x reference)
//
#include <hip/hip_runtime.h>
#include <math.h>

#define D_MODEL 1024
#define SEQ 2048
#define SCALE 0.03125f

using bf16x8 = __attribute__((ext_vector_type(8))) short;
using f32x4  = __attribute__((ext_vector_type(4))) float;

__device__ __forceinline__ unsigned short f2bf(float f) {
  union { float f; unsigned int u; } v; v.f = f;
  return (unsigned short)((v.u + 0x7fffu + ((v.u >> 16) & 1u)) >> 16);
}

__device__ __forceinline__ void async_cp16(const void* g, void* l) {
  __builtin_amdgcn_global_load_lds(
      (const __attribute__((address_space(1))) void*)g,
      (__attribute__((address_space(3))) void*)l, 16, 0, 0);
}

// ============================================================================
// Round-4 proven GEMM core: 128x128 tile, 256 threads (4 waves, 2M x 2N),
// BK=64, double-buffered LDS = 64 KiB -> 2 blocks/CU. LDS swizzle: 16B chunk
// c of row r at phys chunk c^(r&7) (2-way bank alias = free; 0 conflicts
// measured). Staging pre-swizzles the GLOBAL source (global_load_lds writes
// linearly). One __syncthreads per K-tile; drain masked by co-resident block.
// ============================================================================

__device__ __forceinline__ const unsigned short* sptr(
    const unsigned short* base, int row0, int t) {
  const int rr = t >> 3;
  const int ck = (t & 7) ^ (rr & 7);
  return base + (size_t)(row0 + rr) * D_MODEL + ck * 8;
}

#define STG8(KT, BUF) {                                                    \
    const unsigned short* a_ = sA + (KT) * 64;                             \
    const unsigned short* b_ = sB + (KT) * 64;                             \
    unsigned short* da_ = As + (BUF) * 8192 + t * 8;                       \
    unsigned short* db_ = Bs + (BUF) * 8192 + t * 8;                       \
    async_cp16(a_,                 da_);                                   \
    async_cp16(a_ + 32 * D_MODEL,  da_ + 2048);                            \
    async_cp16(a_ + 64 * D_MODEL,  da_ + 4096);                            \
    async_cp16(a_ + 96 * D_MODEL,  da_ + 6144);                            \
    async_cp16(b_,                 db_);                                   \
    async_cp16(b_ + 32 * D_MODEL,  db_ + 2048);                            \
    async_cp16(b_ + 64 * D_MODEL,  db_ + 4096);                            \
    async_cp16(b_ + 96 * D_MODEL,  db_ + 6144);                            \
  }

__device__ __forceinline__ void gemm128_bk64(
    const unsigned short* sA, const unsigned short* sB,
    unsigned short* As, unsigned short* Bs, int t, f32x4 acc[4][4]) {
  const int lane = t & 63, w = t >> 6;
  const int wm = w >> 1, wn = w & 1;
  const int l16 = lane & 15, quad = lane >> 4, x7 = l16 & 7;
  const int c0 = (quad ^ x7) * 8, c1 = ((4 | quad) ^ x7) * 8;

  STG8(0, 0);
  __syncthreads();

  #pragma unroll 2
  for (int kk = 0; kk < 16; ++kk) {
    const int cur = (kk & 1) * 8192;
    if (kk < 15) STG8(kk + 1, (kk & 1) ^ 1);
    bf16x8 afr[4][2], bfr[4][2];
    #pragma unroll
    for (int mt = 0; mt < 4; mt++) {
      const int base = cur + (wm * 64 + mt * 16 + l16) * 64;
      afr[mt][0] = *(const bf16x8*)(As + base + c0);
      afr[mt][1] = *(const bf16x8*)(As + base + c1);
    }
    #pragma unroll
    for (int nt = 0; nt < 4; nt++) {
      const int base = cur + (wn * 64 + nt * 16 + l16) * 64;
      bfr[nt][0] = *(const bf16x8*)(Bs + base + c0);
      bfr[nt][1] = *(const bf16x8*)(Bs + base + c1);
    }
    #pragma unroll
    for (int ks = 0; ks < 2; ks++)
      #pragma unroll
      for (int mt = 0; mt < 4; mt++)
        #pragma unroll
        for (int nt = 0; nt < 4; nt++)
          acc[mt][nt] = __builtin_amdgcn_mfma_f32_16x16x32_bf16(
              afr[mt][ks], bfr[nt][ks], acc[mt][nt], 0, 0, 0);
    __syncthreads();
  }
}

__device__ __forceinline__ void store_c_bf16(f32x4 acc[4][4],
                                             unsigned short* C, int ldc,
                                             int m0, int n0, int tid) {
  const int lane = tid & 63, w = tid >> 6;
  const int wm = w >> 1, wn = w & 1;
  const int l16 = lane & 15, quad = lane >> 4;
  #pragma unroll
  for (int mt = 0; mt < 4; mt++) {
    #pragma unroll
    for (int r = 0; r < 4; r++) {
      const int row = m0 + wm * 64 + mt * 16 + quad * 4 + r;
      unsigned short* cp = C + (size_t)row * ldc + n0 + wn * 64 + l16;
      #pragma unroll
      for (int nt = 0; nt < 4; nt++) cp[nt * 16] = f2bf(acc[mt][nt][r]);
    }
  }
}

// ---- wcvt (r8 proven): one WAVE per W row. Grid 513 x 256. ----
__global__ __launch_bounds__(256) void wcvt_kernel(
    const float* __restrict__ Wq, const float* __restrict__ Wk,
    const float* __restrict__ bq, const float* __restrict__ bk,
    unsigned short* __restrict__ Wqb, unsigned short* __restrict__ Wkb,
    float* __restrict__ u, float* __restrict__ v, float* __restrict__ sc) {
  const int w = threadIdx.x >> 6, l = threadIdx.x & 63;
  if (blockIdx.x < 512) {
    const int row = blockIdx.x * 4 + w;  // 0..2047
    const bool isq = row < 1024;
    const int rr = row & 1023;
    const float* W = isq ? Wq : Wk;
    const float* bias = isq ? bk : bq;
    ushort4* Wo4 = (ushort4*)((isq ? Wqb : Wkb) + (size_t)rr * D_MODEL);
    const float4* Wr4 = (const float4*)(W + (size_t)rr * D_MODEL);
    float p = 0.f;
    #pragma unroll
    for (int i = 0; i < 4; i++) {
      const int idx = i * 64 + l;
      const float4 wv = Wr4[idx];
      const float4 bv = ((const float4*)bias)[idx];
      ushort4 o;
      o.x = f2bf(wv.x); o.y = f2bf(wv.y); o.z = f2bf(wv.z); o.w = f2bf(wv.w);
      Wo4[idx] = o;
      p += wv.x * bv.x + wv.y * bv.y + wv.z * bv.z + wv.w * bv.w;
    }
    #pragma unroll
    for (int off = 32; off > 0; off >>= 1) p += __shfl_down(p, off, 64);
    if (l == 0) (isq ? u : v)[rr] = p;
  } else if (w == 0) {
    float p = 0.f;
    #pragma unroll
    for (int i = 0; i < 4; i++) {
      const int idx = i * 64 + l;
      const float4 a = ((const float4*)bq)[idx];
      const float4 b = ((const float4*)bk)[idx];
      p += a.x * b.x + a.y * b.y + a.z * b.z + a.w * b.w;
    }
    #pragma unroll
    for (int off = 32; off > 0; off >>= 1) p += __shfl_down(p, off, 64);
    if (l == 0) sc[0] = SCALE * p;
  }
}

// ---- prep_x v3: one WAVE per x row, XCD-ALIGNED row ownership. ----
// Block bi (on XCD bi&7) handles rows m = (bi&7)*1024 + (bi>>3)*4 + wave
// -> XCD k writes xb rows [k*1024, k*1024+1024), exactly the A-panel range
// zgen's XCD k will read (100% L2-local first touch). Bijective:
// (bi&7) x (bi>>3 in [0,256)) x wave in [0,4) covers [0,8192).
__global__ __launch_bounds__(256) void prep_x_kernel(
    const float* __restrict__ x, const float* __restrict__ Wo,
    const float* __restrict__ bo, const float* __restrict__ u,
    const float* __restrict__ v, const float* __restrict__ sc,
    unsigned short* __restrict__ xb, float* __restrict__ tb,
    float* __restrict__ aa, float* __restrict__ bb) {
  const int w = threadIdx.x >> 6, l = threadIdx.x & 63;
  const int bi = blockIdx.x;
  const int m = (bi & 7) * 1024 + (bi >> 3) * 4 + w;
  const float4* xr4 = (const float4*)(x + (size_t)m * D_MODEL);
  ushort4* xo4 = (ushort4*)(xb + (size_t)m * D_MODEL);
  float p0 = 0.f, p1 = 0.f, p2 = 0.f;
  #pragma unroll
  for (int i = 0; i < 4; i++) {
    const int idx = i * 64 + l;
    const float4 xv = xr4[idx];
    const float4 wv = ((const float4*)Wo)[idx];
    const float4 uv = ((const float4*)u)[idx];
    const float4 vv = ((const float4*)v)[idx];
    ushort4 o;
    o.x = f2bf(xv.x); o.y = f2bf(xv.y); o.z = f2bf(xv.z); o.w = f2bf(xv.w);
    xo4[idx] = o;
    p0 += xv.x * wv.x + xv.y * wv.y + xv.z * wv.z + xv.w * wv.w;
    p1 += xv.x * uv.x + xv.y * uv.y + xv.z * uv.z + xv.w * uv.w;
    p2 += xv.x * vv.x + xv.y * vv.y + xv.z * vv.z + xv.w * vv.w;
  }
  #pragma unroll
  for (int off = 32; off > 0; off >>= 1) {
    p0 += __shfl_down(p0, off, 64);
    p1 += __shfl_down(p1, off, 64);
    p2 += __shfl_down(p2, off, 64);
  }
  if (l == 0) {
    tb[m] = tanhf(p0 + bo[0]);
    aa[m] = SCALE * p1 + sc[0];
    bb[m] = SCALE * p2;
  }
}

// ---- wmm (r9 proven): 64x64 tiles -> 256 blocks. ----
__global__ __launch_bounds__(256, 2) void wmm_kernel(
    const unsigned short* __restrict__ Wkb,
    const unsigned short* __restrict__ Wqb, unsigned short* __restrict__ Mt) {
  const int m0 = blockIdx.x * 64, n0 = blockIdx.y * 64;
  __shared__ unsigned short As[2 * 4096], Bs[2 * 4096];
  const int t = threadIdx.x;
  const int lane = t & 63, w = t >> 6;
  const int wm = w >> 1, wn = w & 1;
  const int l16 = lane & 15, quad = lane >> 4, x7 = l16 & 7;
  const int c0 = (quad ^ x7) * 8, c1 = ((4 | quad) ^ x7) * 8;
  const unsigned short* sA = sptr(Wkb, m0, t);
  const unsigned short* sB = sptr(Wqb, n0, t);

  #define STG4W(KT, BUF) {                                                 \
      const unsigned short* a_ = sA + (KT) * 64;                           \
      const unsigned short* b_ = sB + (KT) * 64;                           \
      unsigned short* da_ = As + (BUF) * 4096 + t * 8;                     \
      unsigned short* db_ = Bs + (BUF) * 4096 + t * 8;                     \
      async_cp16(a_,                da_);                                  \
      async_cp16(a_ + 32 * D_MODEL, da_ + 2048);                           \
      async_cp16(b_,                db_);                                  \
      async_cp16(b_ + 32 * D_MODEL, db_ + 2048);                           \
    }

  f32x4 acc[2][2];
  #pragma unroll
  for (int i = 0; i < 2; i++)
    #pragma unroll
    for (int j = 0; j < 2; j++) acc[i][j] = f32x4{0.f, 0.f, 0.f, 0.f};

  STG4W(0, 0);
  __syncthreads();
  #pragma unroll 2
  for (int kk = 0; kk < 16; ++kk) {
    const int cur = (kk & 1) * 4096;
    if (kk < 15) STG4W(kk + 1, (kk & 1) ^ 1);
    bf16x8 afr[2][2], bfr[2][2];
    #pragma unroll
    for (int mt = 0; mt < 2; mt++) {
      const int base = cur + (wm * 32 + mt * 16 + l16) * 64;
      afr[mt][0] = *(const bf16x8*)(As + base + c0);
      afr[mt][1] = *(const bf16x8*)(As + base + c1);
    }
    #pragma unroll
    for (int nt = 0; nt < 2; nt++) {
      const int base = cur + (wn * 32 + nt * 16 + l16) * 64;
      bfr[nt][0] = *(const bf16x8*)(Bs + base + c0);
      bfr[nt][1] = *(const bf16x8*)(Bs + base + c1);
    }
    #pragma unroll
    for (int ks = 0; ks < 2; ks++)
      #pragma unroll
      for (int mt = 0; mt < 2; mt++)
        #pragma unroll
        for (int nt = 0; nt < 2; nt++)
          acc[mt][nt] = __builtin_amdgcn_mfma_f32_16x16x32_bf16(
              afr[mt][ks], bfr[nt][ks], acc[mt][nt], 0, 0, 0);
    __syncthreads();
  }

  #pragma unroll
  for (int mt = 0; mt < 2; mt++) {
    #pragma unroll
    for (int r = 0; r < 4; r++) {
      const int row = m0 + wm * 32 + mt * 16 + quad * 4 + r;
      unsigned short* cp = Mt + (size_t)row * D_MODEL + n0 + wn * 32 + l16;
      #pragma unroll
      for (int nt = 0; nt < 2; nt++) cp[nt * 16] = f2bf(acc[mt][nt][r]);
    }
  }
}

// ---- zgen (r9 proven map): XCD k computes/writes Zb rows k*1024..+1023;
// A-panel (xb) reads are now 100% L2-local thanks to prep_x v3 alignment. ----
__global__ __launch_bounds__(256, 2) void zgen_kernel(
    const unsigned short* __restrict__ xb,
    const unsigned short* __restrict__ Mt, unsigned short* __restrict__ Zb) {
  const int id = blockIdx.y * 64 + blockIdx.x;
  const int xcd = id & 7, q = id >> 3;
  const int m0 = (xcd * 8 + (q & 7)) * 128;
  const int n0 = (q >> 3) * 128;
  __shared__ unsigned short As[2 * 8192], Bs[2 * 8192];
  const int t = threadIdx.x;
  f32x4 acc[4][4];
  #pragma unroll
  for (int i = 0; i < 4; i++)
    #pragma unroll
    for (int j = 0; j < 4; j++) acc[i][j] = f32x4{0.f, 0.f, 0.f, 0.f};
  gemm128_bk64(sptr(xb, m0, t), sptr(Mt, n0, t), As, Bs, t, acc);
  store_c_bf16(acc, Zb, D_MODEL, m0, n0, t);
}

// ---- zxt: r4 core + XCD map ALIGNED to zgen's Zb ownership. ----
// XCD k (= n&7) handles batch b = k>>1, i-half = k&1 -> its Zb A-panels are
// exactly global rows [k*1024, k*1024+1024), written by zgen on XCD k
// (L2-local). Per-XCD sequence s = n>>3 (0..127): jgroup = s>>5 (4 j-panels),
// ii = (s>>2)&7 (8 i-panels), jj = s&3 -> instantaneous working set while
// scanning a jgroup: 8 A (2 MiB) + 4 B (1 MiB) = 3 MiB <= 4 MiB L2.
// Bijective: 8 xcd x 4 jgroup x 8 ii x 4 jj = 1024.
__global__ __launch_bounds__(256, 2) void zxt_kernel(
    const unsigned short* __restrict__ Zb, const unsigned short* __restrict__ xb,
    const float* __restrict__ tb, const float* __restrict__ aa,
    const float* __restrict__ bb, float* __restrict__ out) {
  __shared__ unsigned short As[2 * 8192], Bs[2 * 8192];
  __shared__ float tsi[128], tsa[128], tsj[128], tsb2[128];
  const int n = blockIdx.z * 256 + blockIdx.y * 16 + blockIdx.x;
  const int xcd = n & 7, s = n >> 3;
  const int b = xcd >> 1;
  const int i0 = ((xcd & 1) * 8 + ((s >> 2) & 7)) * 128;
  const int j0 = ((s >> 5) * 4 + (s & 3)) * 128;
  const int t = threadIdx.x;

  if (t < 128) {
    tsi[t] = tb[b * SEQ + i0 + t];
    tsa[t] = aa[b * SEQ + i0 + t];
  } else {
    tsj[t - 128] = tb[b * SEQ + j0 + t - 128];
    tsb2[t - 128] = bb[b * SEQ + j0 + t - 128];
  }

  f32x4 acc[4][4];
  #pragma unroll
  for (int i = 0; i < 4; i++)
    #pragma unroll
    for (int j = 0; j < 4; j++) acc[i][j] = f32x4{0.f, 0.f, 0.f, 0.f};
  gemm128_bk64(sptr(Zb + (size_t)b * SEQ * D_MODEL, i0, t),
               sptr(xb + (size_t)b * SEQ * D_MODEL, j0, t), As, Bs, t, acc);

  const int lane = t & 63, w = t >> 6;
  const int wm = w >> 1, wn = w & 1;
  const int l16 = lane & 15, quad = lane >> 4;
  float tj[4], bj[4];
  #pragma unroll
  for (int nt = 0; nt < 4; nt++) {
    tj[nt] = tsj[wn * 64 + nt * 16 + l16];
    bj[nt] = tsb2[wn * 64 + nt * 16 + l16];
  }
  #pragma unroll
  for (int mt = 0; mt < 4; mt++) {
    #pragma unroll
    for (int rr = 0; rr < 4; rr++) {
      const int il = wm * 64 + mt * 16 + quad * 4 + rr;
      const float ti = tsi[il];
      const float ai = tsa[il];
      float* cp =
          out + ((size_t)(b * SEQ + i0 + il)) * SEQ + j0 + wn * 64 + l16;
      #pragma unroll
      for (int nt = 0; nt < 4; nt++) {
        const float num = tj[nt] - ti;
        const float den = fmaf(-tj[nt], ti, 1.0f);
        const float obias = 5.0f * num * __builtin_amdgcn_rcpf(den);
        cp[nt * 16] = SCALE * acc[mt][nt][rr] + ai + bj[nt] + obias;
      }
    }
  }
}

extern "C" void kernel_launch(void* const* d_in, const int* in_sizes, int n_in,
                              void* d_out, int out_size, void* d_ws,
                              size_t ws_size, hipStream_t stream) {
  const float* x  = (const float*)d_in[0];
  const float* Wq = (const float*)d_in[1];
  const float* bq = (const float*)d_in[2];
  const float* Wk = (const float*)d_in[3];
  const float* bk = (const float*)d_in[4];
  const float* Wo = (const float*)d_in[5];
  const float* bo = (const float*)d_in[6];
  float* out = (float*)d_out;

  char* ws = (char*)d_ws;
  unsigned short* xb  = (unsigned short*)(ws);                      // 16 MiB
  unsigned short* Zb  = (unsigned short*)(ws + (16ull << 20));      // 16 MiB
  unsigned short* Wqb = (unsigned short*)(ws + (32ull << 20));      // 2 MiB
  unsigned short* Wkb = (unsigned short*)(ws + (34ull << 20));      // 2 MiB
  unsigned short* Mt  = (unsigned short*)(ws + (36ull << 20));      // 2 MiB
  float* tb = (float*)(ws + (38ull << 20));                         // 32 KiB
  float* aa = (float*)(ws + (38ull << 20) + (32ull << 10));         // 32 KiB
  float* bb = (float*)(ws + (38ull << 20) + (64ull << 10));         // 32 KiB
  float* u  = (float*)(ws + (38ull << 20) + (96ull << 10));         // 4 KiB
  float* v  = (float*)(ws + (38ull << 20) + (100ull << 10));        // 4 KiB
  float* sc = (float*)(ws + (38ull << 20) + (104ull << 10));        // 4 B

  wcvt_kernel<<<513, 256, 0, stream>>>(Wq, Wk, bq, bk, Wqb, Wkb, u, v, sc);
  prep_x_kernel<<<2048, 256, 0, stream>>>(x, Wo, bo, u, v, sc, xb, tb, aa, bb);
  wmm_kernel<<<dim3(16, 16), 256, 0, stream>>>(Wkb, Wqb, Mt);
  zgen_kernel<<<dim3(64, 8), 256, 0, stream>>>(xb, Mt, Zb);
  zxt_kernel<<<dim3(16, 16, 4), 256, 0, stream>>>(Zb, xb, tb, aa, bb, out);
}

// Round 11
// 182.419 us; speedup vs baseline: 1.0122x; 1.0122x over previous
//
#include <hip/hip_runtime.h>
#include <math.h>

#define D_MODEL 1024
#define SEQ 2048
#define SCALE 0.03125f

using bf16x8 = __attribute__((ext_vector_type(8))) short;
using f32x4  = __attribute__((ext_vector_type(4))) float;

__device__ __forceinline__ unsigned short f2bf(float f) {
  union { float f; unsigned int u; } v; v.f = f;
  return (unsigned short)((v.u + 0x7fffu + ((v.u >> 16) & 1u)) >> 16);
}

__device__ __forceinline__ void async_cp16(const void* g, void* l) {
  __builtin_amdgcn_global_load_lds(
      (const __attribute__((address_space(1))) void*)g,
      (__attribute__((address_space(3))) void*)l, 16, 0, 0);
}

// ============================================================================
// Round-4 proven GEMM core: 128x128 tile, 256 threads (4 waves, 2M x 2N),
// BK=64, double-buffered LDS = 64 KiB -> 2 blocks/CU. LDS swizzle: 16B chunk
// c of row r at phys chunk c^(r&7) (2-way bank alias = free; 0 conflicts
// measured). Staging pre-swizzles the GLOBAL source (global_load_lds writes
// linearly). One __syncthreads per K-tile; drain masked by co-resident block.
// ============================================================================

__device__ __forceinline__ const unsigned short* sptr(
    const unsigned short* base, int row0, int t) {
  const int rr = t >> 3;
  const int ck = (t & 7) ^ (rr & 7);
  return base + (size_t)(row0 + rr) * D_MODEL + ck * 8;
}

#define STG8(KT, BUF) {                                                    \
    const unsigned short* a_ = sA + (KT) * 64;                             \
    const unsigned short* b_ = sB + (KT) * 64;                             \
    unsigned short* da_ = As + (BUF) * 8192 + t * 8;                       \
    unsigned short* db_ = Bs + (BUF) * 8192 + t * 8;                       \
    async_cp16(a_,                 da_);                                   \
    async_cp16(a_ + 32 * D_MODEL,  da_ + 2048);                            \
    async_cp16(a_ + 64 * D_MODEL,  da_ + 4096);                            \
    async_cp16(a_ + 96 * D_MODEL,  da_ + 6144);                            \
    async_cp16(b_,                 db_);                                   \
    async_cp16(b_ + 32 * D_MODEL,  db_ + 2048);                            \
    async_cp16(b_ + 64 * D_MODEL,  db_ + 4096);                            \
    async_cp16(b_ + 96 * D_MODEL,  db_ + 6144);                            \
  }

__device__ __forceinline__ void gemm128_bk64(
    const unsigned short* sA, const unsigned short* sB,
    unsigned short* As, unsigned short* Bs, int t, f32x4 acc[4][4]) {
  const int lane = t & 63, w = t >> 6;
  const int wm = w >> 1, wn = w & 1;
  const int l16 = lane & 15, quad = lane >> 4, x7 = l16 & 7;
  const int c0 = (quad ^ x7) * 8, c1 = ((4 | quad) ^ x7) * 8;

  STG8(0, 0);
  __syncthreads();

  #pragma unroll 2
  for (int kk = 0; kk < 16; ++kk) {
    const int cur = (kk & 1) * 8192;
    if (kk < 15) STG8(kk + 1, (kk & 1) ^ 1);
    bf16x8 afr[4][2], bfr[4][2];
    #pragma unroll
    for (int mt = 0; mt < 4; mt++) {
      const int base = cur + (wm * 64 + mt * 16 + l16) * 64;
      afr[mt][0] = *(const bf16x8*)(As + base + c0);
      afr[mt][1] = *(const bf16x8*)(As + base + c1);
    }
    #pragma unroll
    for (int nt = 0; nt < 4; nt++) {
      const int base = cur + (wn * 64 + nt * 16 + l16) * 64;
      bfr[nt][0] = *(const bf16x8*)(Bs + base + c0);
      bfr[nt][1] = *(const bf16x8*)(Bs + base + c1);
    }
    #pragma unroll
    for (int ks = 0; ks < 2; ks++)
      #pragma unroll
      for (int mt = 0; mt < 4; mt++)
        #pragma unroll
        for (int nt = 0; nt < 4; nt++)
          acc[mt][nt] = __builtin_amdgcn_mfma_f32_16x16x32_bf16(
              afr[mt][ks], bfr[nt][ks], acc[mt][nt], 0, 0, 0);
    __syncthreads();
  }
}

__device__ __forceinline__ void store_c_bf16(f32x4 acc[4][4],
                                             unsigned short* C, int ldc,
                                             int m0, int n0, int tid) {
  const int lane = tid & 63, w = tid >> 6;
  const int wm = w >> 1, wn = w & 1;
  const int l16 = lane & 15, quad = lane >> 4;
  #pragma unroll
  for (int mt = 0; mt < 4; mt++) {
    #pragma unroll
    for (int r = 0; r < 4; r++) {
      const int row = m0 + wm * 64 + mt * 16 + quad * 4 + r;
      unsigned short* cp = C + (size_t)row * ldc + n0 + wn * 64 + l16;
      #pragma unroll
      for (int nt = 0; nt < 4; nt++) cp[nt * 16] = f2bf(acc[mt][nt][r]);
    }
  }
}

// ---- wcvt (r8 proven): one WAVE per W row. Grid 513 x 256. ----
__global__ __launch_bounds__(256) void wcvt_kernel(
    const float* __restrict__ Wq, const float* __restrict__ Wk,
    const float* __restrict__ bq, const float* __restrict__ bk,
    unsigned short* __restrict__ Wqb, unsigned short* __restrict__ Wkb,
    float* __restrict__ u, float* __restrict__ v, float* __restrict__ sc) {
  const int w = threadIdx.x >> 6, l = threadIdx.x & 63;
  if (blockIdx.x < 512) {
    const int row = blockIdx.x * 4 + w;  // 0..2047
    const bool isq = row < 1024;
    const int rr = row & 1023;
    const float* W = isq ? Wq : Wk;
    const float* bias = isq ? bk : bq;
    ushort4* Wo4 = (ushort4*)((isq ? Wqb : Wkb) + (size_t)rr * D_MODEL);
    const float4* Wr4 = (const float4*)(W + (size_t)rr * D_MODEL);
    float p = 0.f;
    #pragma unroll
    for (int i = 0; i < 4; i++) {
      const int idx = i * 64 + l;
      const float4 wv = Wr4[idx];
      const float4 bv = ((const float4*)bias)[idx];
      ushort4 o;
      o.x = f2bf(wv.x); o.y = f2bf(wv.y); o.z = f2bf(wv.z); o.w = f2bf(wv.w);
      Wo4[idx] = o;
      p += wv.x * bv.x + wv.y * bv.y + wv.z * bv.z + wv.w * bv.w;
    }
    #pragma unroll
    for (int off = 32; off > 0; off >>= 1) p += __shfl_down(p, off, 64);
    if (l == 0) (isq ? u : v)[rr] = p;
  } else if (w == 0) {
    float p = 0.f;
    #pragma unroll
    for (int i = 0; i < 4; i++) {
      const int idx = i * 64 + l;
      const float4 a = ((const float4*)bq)[idx];
      const float4 b = ((const float4*)bk)[idx];
      p += a.x * b.x + a.y * b.y + a.z * b.z + a.w * b.w;
    }
    #pragma unroll
    for (int off = 32; off > 0; off >>= 1) p += __shfl_down(p, off, 64);
    if (l == 0) sc[0] = SCALE * p;
  }
}

// ---- prep_x v2 (r8/r9 proven): one WAVE per x row, linear map. ----
__global__ __launch_bounds__(256) void prep_x_kernel(
    const float* __restrict__ x, const float* __restrict__ Wo,
    const float* __restrict__ bo, const float* __restrict__ u,
    const float* __restrict__ v, const float* __restrict__ sc,
    unsigned short* __restrict__ xb, float* __restrict__ tb,
    float* __restrict__ aa, float* __restrict__ bb) {
  const int w = threadIdx.x >> 6, l = threadIdx.x & 63;
  const int m = blockIdx.x * 4 + w;
  const float4* xr4 = (const float4*)(x + (size_t)m * D_MODEL);
  ushort4* xo4 = (ushort4*)(xb + (size_t)m * D_MODEL);
  float p0 = 0.f, p1 = 0.f, p2 = 0.f;
  #pragma unroll
  for (int i = 0; i < 4; i++) {
    const int idx = i * 64 + l;
    const float4 xv = xr4[idx];
    const float4 wv = ((const float4*)Wo)[idx];
    const float4 uv = ((const float4*)u)[idx];
    const float4 vv = ((const float4*)v)[idx];
    ushort4 o;
    o.x = f2bf(xv.x); o.y = f2bf(xv.y); o.z = f2bf(xv.z); o.w = f2bf(xv.w);
    xo4[idx] = o;
    p0 += xv.x * wv.x + xv.y * wv.y + xv.z * wv.z + xv.w * wv.w;
    p1 += xv.x * uv.x + xv.y * uv.y + xv.z * uv.z + xv.w * uv.w;
    p2 += xv.x * vv.x + xv.y * vv.y + xv.z * vv.z + xv.w * vv.w;
  }
  #pragma unroll
  for (int off = 32; off > 0; off >>= 1) {
    p0 += __shfl_down(p0, off, 64);
    p1 += __shfl_down(p1, off, 64);
    p2 += __shfl_down(p2, off, 64);
  }
  if (l == 0) {
    tb[m] = tanhf(p0 + bo[0]);
    aa[m] = SCALE * p1 + sc[0];
    bb[m] = SCALE * p2;
  }
}

// ---- wmm (r9 proven): 64x64 tiles -> 256 blocks. ----
__global__ __launch_bounds__(256, 2) void wmm_kernel(
    const unsigned short* __restrict__ Wkb,
    const unsigned short* __restrict__ Wqb, unsigned short* __restrict__ Mt) {
  const int m0 = blockIdx.x * 64, n0 = blockIdx.y * 64;
  __shared__ unsigned short As[2 * 4096], Bs[2 * 4096];
  const int t = threadIdx.x;
  const int lane = t & 63, w = t >> 6;
  const int wm = w >> 1, wn = w & 1;
  const int l16 = lane & 15, quad = lane >> 4, x7 = l16 & 7;
  const int c0 = (quad ^ x7) * 8, c1 = ((4 | quad) ^ x7) * 8;
  const unsigned short* sA = sptr(Wkb, m0, t);
  const unsigned short* sB = sptr(Wqb, n0, t);

  #define STG4W(KT, BUF) {                                                 \
      const unsigned short* a_ = sA + (KT) * 64;                           \
      const unsigned short* b_ = sB + (KT) * 64;                           \
      unsigned short* da_ = As + (BUF) * 4096 + t * 8;                     \
      unsigned short* db_ = Bs + (BUF) * 4096 + t * 8;                     \
      async_cp16(a_,                da_);                                  \
      async_cp16(a_ + 32 * D_MODEL, da_ + 2048);                           \
      async_cp16(b_,                db_);                                  \
      async_cp16(b_ + 32 * D_MODEL, db_ + 2048);                           \
    }

  f32x4 acc[2][2];
  #pragma unroll
  for (int i = 0; i < 2; i++)
    #pragma unroll
    for (int j = 0; j < 2; j++) acc[i][j] = f32x4{0.f, 0.f, 0.f, 0.f};

  STG4W(0, 0);
  __syncthreads();
  #pragma unroll 2
  for (int kk = 0; kk < 16; ++kk) {
    const int cur = (kk & 1) * 4096;
    if (kk < 15) STG4W(kk + 1, (kk & 1) ^ 1);
    bf16x8 afr[2][2], bfr[2][2];
    #pragma unroll
    for (int mt = 0; mt < 2; mt++) {
      const int base = cur + (wm * 32 + mt * 16 + l16) * 64;
      afr[mt][0] = *(const bf16x8*)(As + base + c0);
      afr[mt][1] = *(const bf16x8*)(As + base + c1);
    }
    #pragma unroll
    for (int nt = 0; nt < 2; nt++) {
      const int base = cur + (wn * 32 + nt * 16 + l16) * 64;
      bfr[nt][0] = *(const bf16x8*)(Bs + base + c0);
      bfr[nt][1] = *(const bf16x8*)(Bs + base + c1);
    }
    #pragma unroll
    for (int ks = 0; ks < 2; ks++)
      #pragma unroll
      for (int mt = 0; mt < 2; mt++)
        #pragma unroll
        for (int nt = 0; nt < 2; nt++)
          acc[mt][nt] = __builtin_amdgcn_mfma_f32_16x16x32_bf16(
              afr[mt][ks], bfr[nt][ks], acc[mt][nt], 0, 0, 0);
    __syncthreads();
  }

  #pragma unroll
  for (int mt = 0; mt < 2; mt++) {
    #pragma unroll
    for (int r = 0; r < 4; r++) {
      const int row = m0 + wm * 32 + mt * 16 + quad * 4 + r;
      unsigned short* cp = Mt + (size_t)row * D_MODEL + n0 + wn * 32 + l16;
      #pragma unroll
      for (int nt = 0; nt < 2; nt++) cp[nt * 16] = f2bf(acc[mt][nt][r]);
    }
  }
}

// ---- zgen (r9 proven map): XCD k computes/writes Zb rows k*1024..+1023 ----
__global__ __launch_bounds__(256, 2) void zgen_kernel(
    const unsigned short* __restrict__ xb,
    const unsigned short* __restrict__ Mt, unsigned short* __restrict__ Zb) {
  const int id = blockIdx.y * 64 + blockIdx.x;
  const int xcd = id & 7, q = id >> 3;
  const int m0 = (xcd * 8 + (q & 7)) * 128;
  const int n0 = (q >> 3) * 128;
  __shared__ unsigned short As[2 * 8192], Bs[2 * 8192];
  const int t = threadIdx.x;
  f32x4 acc[4][4];
  #pragma unroll
  for (int i = 0; i < 4; i++)
    #pragma unroll
    for (int j = 0; j < 4; j++) acc[i][j] = f32x4{0.f, 0.f, 0.f, 0.f};
  gemm128_bk64(sptr(xb, m0, t), sptr(Mt, n0, t), As, Bs, t, acc);
  store_c_bf16(acc, Zb, D_MODEL, m0, n0, t);
}

// ---- zxt (r10 proven): r4 core + XCD map aligned to zgen's Zb ownership ----
// XCD k (= n&7): batch b = k>>1, i-half = k&1 -> its Zb A-panels are global
// rows [k*1024, k*1024+1024), written by zgen on XCD k (L2-local; FETCH
// measured 49.4 -> 32.9 MB). Per-XCD sequence s = n>>3: jgroup = s>>5,
// ii = (s>>2)&7, jj = s&3 -> instantaneous set 8 A + 4 B = 3 MiB <= 4 MiB L2.
// Bijective: 8 xcd x 4 jgroup x 8 ii x 4 jj = 1024.
__global__ __launch_bounds__(256, 2) void zxt_kernel(
    const unsigned short* __restrict__ Zb, const unsigned short* __restrict__ xb,
    const float* __restrict__ tb, const float* __restrict__ aa,
    const float* __restrict__ bb, float* __restrict__ out) {
  __shared__ unsigned short As[2 * 8192], Bs[2 * 8192];
  __shared__ float tsi[128], tsa[128], tsj[128], tsb2[128];
  const int n = blockIdx.z * 256 + blockIdx.y * 16 + blockIdx.x;
  const int xcd = n & 7, s = n >> 3;
  const int b = xcd >> 1;
  const int i0 = ((xcd & 1) * 8 + ((s >> 2) & 7)) * 128;
  const int j0 = ((s >> 5) * 4 + (s & 3)) * 128;
  const int t = threadIdx.x;

  if (t < 128) {
    tsi[t] = tb[b * SEQ + i0 + t];
    tsa[t] = aa[b * SEQ + i0 + t];
  } else {
    tsj[t - 128] = tb[b * SEQ + j0 + t - 128];
    tsb2[t - 128] = bb[b * SEQ + j0 + t - 128];
  }

  f32x4 acc[4][4];
  #pragma unroll
  for (int i = 0; i < 4; i++)
    #pragma unroll
    for (int j = 0; j < 4; j++) acc[i][j] = f32x4{0.f, 0.f, 0.f, 0.f};
  gemm128_bk64(sptr(Zb + (size_t)b * SEQ * D_MODEL, i0, t),
               sptr(xb + (size_t)b * SEQ * D_MODEL, j0, t), As, Bs, t, acc);

  const int lane = t & 63, w = t >> 6;
  const int wm = w >> 1, wn = w & 1;
  const int l16 = lane & 15, quad = lane >> 4;
  float tj[4], bj[4];
  #pragma unroll
  for (int nt = 0; nt < 4; nt++) {
    tj[nt] = tsj[wn * 64 + nt * 16 + l16];
    bj[nt] = tsb2[wn * 64 + nt * 16 + l16];
  }
  #pragma unroll
  for (int mt = 0; mt < 4; mt++) {
    #pragma unroll
    for (int rr = 0; rr < 4; rr++) {
      const int il = wm * 64 + mt * 16 + quad * 4 + rr;
      const float ti = tsi[il];
      const float ai = tsa[il];
      float* cp =
          out + ((size_t)(b * SEQ + i0 + il)) * SEQ + j0 + wn * 64 + l16;
      #pragma unroll
      for (int nt = 0; nt < 4; nt++) {
        const float num = tj[nt] - ti;
        const float den = fmaf(-tj[nt], ti, 1.0f);
        const float obias = 5.0f * num * __builtin_amdgcn_rcpf(den);
        cp[nt * 16] = SCALE * acc[mt][nt][rr] + ai + bj[nt] + obias;
      }
    }
  }
}

extern "C" void kernel_launch(void* const* d_in, const int* in_sizes, int n_in,
                              void* d_out, int out_size, void* d_ws,
                              size_t ws_size, hipStream_t stream) {
  const float* x  = (const float*)d_in[0];
  const float* Wq = (const float*)d_in[1];
  const float* bq = (const float*)d_in[2];
  const float* Wk = (const float*)d_in[3];
  const float* bk = (const float*)d_in[4];
  const float* Wo = (const float*)d_in[5];
  const float* bo = (const float*)d_in[6];
  float* out = (float*)d_out;

  char* ws = (char*)d_ws;
  unsigned short* xb  = (unsigned short*)(ws);                      // 16 MiB
  unsigned short* Zb  = (unsigned short*)(ws + (16ull << 20));      // 16 MiB
  unsigned short* Wqb = (unsigned short*)(ws + (32ull << 20));      // 2 MiB
  unsigned short* Wkb = (unsigned short*)(ws + (34ull << 20));      // 2 MiB
  unsigned short* Mt  = (unsigned short*)(ws + (36ull << 20));      // 2 MiB
  float* tb = (float*)(ws + (38ull << 20));                         // 32 KiB
  float* aa = (float*)(ws + (38ull << 20) + (32ull << 10));         // 32 KiB
  float* bb = (float*)(ws + (38ull << 20) + (64ull << 10));         // 32 KiB
  float* u  = (float*)(ws + (38ull << 20) + (96ull << 10));         // 4 KiB
  float* v  = (float*)(ws + (38ull << 20) + (100ull << 10));        // 4 KiB
  float* sc = (float*)(ws + (38ull << 20) + (104ull << 10));        // 4 B

  wcvt_kernel<<<513, 256, 0, stream>>>(Wq, Wk, bq, bk, Wqb, Wkb, u, v, sc);
  prep_x_kernel<<<2048, 256, 0, stream>>>(x, Wo, bo, u, v, sc, xb, tb, aa, bb);
  wmm_kernel<<<dim3(16, 16), 256, 0, stream>>>(Wkb, Wqb, Mt);
  zgen_kernel<<<dim3(64, 8), 256, 0, stream>>>(xb, Mt, Zb);
  zxt_kernel<<<dim3(16, 16, 4), 256, 0, stream>>>(Zb, xb, tb, aa, bb, out);
}